// Round 1
// baseline (3482.281 us; speedup 1.0000x reference)
//
#include <hip/hip_runtime.h>
#include <stdint.h>
#include <stddef.h>

// ---------------------------------------------------------------------------
// GRBM Gibbs sampling: exact replication of JAX threefry2x32 PRNG (partitionable
// variant) + fp32 tiled GEMMs with fused sampling epilogues.
// B=4096, V=3072, H=512, NUM_STEPS=8.
// ---------------------------------------------------------------------------

#define TS 64
#define KT 16

__host__ __device__ inline void threefry2x32(uint32_t k0, uint32_t k1,
                                             uint32_t x0, uint32_t x1,
                                             uint32_t& o0, uint32_t& o1) {
  uint32_t ks2 = k0 ^ k1 ^ 0x1BD11BDAu;
  x0 += k0; x1 += k1;
#define TFR(r) { x0 += x1; x1 = (x1 << (r)) | (x1 >> (32 - (r))); x1 ^= x0; }
  TFR(13) TFR(15) TFR(26) TFR(6)
  x0 += k1;  x1 += ks2 + 1u;
  TFR(17) TFR(29) TFR(16) TFR(24)
  x0 += ks2; x1 += k0 + 2u;
  TFR(13) TFR(15) TFR(26) TFR(6)
  x0 += k0;  x1 += k1 + 3u;
  TFR(17) TFR(29) TFR(16) TFR(24)
  x0 += k1;  x1 += ks2 + 4u;
  TFR(13) TFR(15) TFR(26) TFR(6)
  x0 += ks2; x1 += k0 + 5u;
#undef TFR
  o0 = x0; o1 = x1;
}

// JAX partitionable random_bits (32-bit): element i -> xor of the two
// threefry outputs with count (hi32(i), lo32(i)). i < 2^32 here so hi=0.
__device__ inline uint32_t jax_bits32(uint32_t key0, uint32_t key1, uint32_t idx) {
  uint32_t o0, o1;
  threefry2x32(key0, key1, 0u, idx, o0, o1);
  return o0 ^ o1;
}

// uniform [0,1): (bits>>9)|0x3f800000 bitcast - 1.0
__device__ inline float jax_uniform01(uint32_t key0, uint32_t key1, uint32_t idx) {
  uint32_t bits = jax_bits32(key0, key1, idx);
  return __uint_as_float((bits >> 9) | 0x3f800000u) - 1.0f;
}

// XLA f32 ErfInv (Giles polynomial) — matches xla/client/lib/math.cc
__device__ inline float erfinv_xla(float x) {
  float w = -log1pf(-x * x);
  float p;
  if (w < 5.0f) {
    w = w - 2.5f;
    p = 2.81022636e-08f;
    p = fmaf(p, w, 3.43273939e-07f);
    p = fmaf(p, w, -3.5233877e-06f);
    p = fmaf(p, w, -4.39150654e-06f);
    p = fmaf(p, w, 0.00021858087f);
    p = fmaf(p, w, -0.00125372503f);
    p = fmaf(p, w, -0.00417768164f);
    p = fmaf(p, w, 0.246640727f);
    p = fmaf(p, w, 1.50140941f);
  } else {
    w = sqrtf(w) - 3.0f;
    p = -0.000200214257f;
    p = fmaf(p, w, 0.000100950558f);
    p = fmaf(p, w, 0.00134934322f);
    p = fmaf(p, w, -0.00367342844f);
    p = fmaf(p, w, 0.00573950773f);
    p = fmaf(p, w, -0.0076224613f);
    p = fmaf(p, w, 0.00943887047f);
    p = fmaf(p, w, 1.00167406f);
    p = fmaf(p, w, 2.83297682f);
  }
  return p * x;
}

// prep: var = max(exp(log_var), 1e-8); invvar = 1/var; std = sqrt(var)
__global__ void prep_kernel(const float* __restrict__ log_var,
                            float* __restrict__ invvar,
                            float* __restrict__ stdv, int V) {
  int i = blockIdx.x * 256 + threadIdx.x;
  if (i < V) {
    float var = fmaxf(expf(log_var[i]), 1e-8f);
    invvar[i] = 1.0f / var;
    stdv[i] = sqrtf(var);
  }
}

// GEMM1: logits = (Vin * invvar) @ W + b ; p = sigmoid(logits); H = bern(kb)
// Vin [M x K] row-major (K = V = 3072), W [K x N] row-major (N = H = 512)
__global__ __launch_bounds__(256)
void gemm_logit_bern(const float* __restrict__ Vin, const float* __restrict__ Wm,
                     const float* __restrict__ bias, const float* __restrict__ invvar,
                     uint8_t* __restrict__ Hout,
                     uint32_t kb0, uint32_t kb1, int M, int N, int K) {
  __shared__ float As[KT][TS];
  __shared__ float Bs[KT][TS];
  const int tid = threadIdx.x;
  const int tx = tid & 15, ty = tid >> 4;
  const int mBase = blockIdx.y * TS, nBase = blockIdx.x * TS;
  float acc[4][4] = {};
  const int la_m = tid >> 2;         // 0..63
  const int la_k = (tid & 3) * 4;    // 0,4,8,12
  const int lb_k = tid >> 4;         // 0..15
  const int lb_n = (tid & 15) * 4;   // 0..60

  for (int k0 = 0; k0 < K; k0 += KT) {
    float4 av = *reinterpret_cast<const float4*>(&Vin[(size_t)(mBase + la_m) * K + k0 + la_k]);
    float4 iv = *reinterpret_cast<const float4*>(&invvar[k0 + la_k]);
    As[la_k + 0][la_m] = av.x * iv.x;
    As[la_k + 1][la_m] = av.y * iv.y;
    As[la_k + 2][la_m] = av.z * iv.z;
    As[la_k + 3][la_m] = av.w * iv.w;
    float4 bv = *reinterpret_cast<const float4*>(&Wm[(size_t)(k0 + lb_k) * N + nBase + lb_n]);
    *reinterpret_cast<float4*>(&Bs[lb_k][lb_n]) = bv;
    __syncthreads();
#pragma unroll
    for (int kk = 0; kk < KT; ++kk) {
      float4 a = *reinterpret_cast<const float4*>(&As[kk][ty * 4]);
      float4 b = *reinterpret_cast<const float4*>(&Bs[kk][tx * 4]);
      float ar[4] = {a.x, a.y, a.z, a.w};
      float br[4] = {b.x, b.y, b.z, b.w};
#pragma unroll
      for (int i = 0; i < 4; ++i)
#pragma unroll
        for (int j = 0; j < 4; ++j)
          acc[i][j] = fmaf(ar[i], br[j], acc[i][j]);
    }
    __syncthreads();
  }

#pragma unroll
  for (int i = 0; i < 4; ++i) {
    int row = mBase + ty * 4 + i;
#pragma unroll
    for (int j = 0; j < 4; ++j) {
      int col = nBase + tx * 4 + j;
      float logit = acc[i][j] + bias[col];
      float p = 0.5f + 0.5f * tanhf(0.5f * logit);   // XLA LogisticExpander form
      uint32_t idx = (uint32_t)row * (uint32_t)N + (uint32_t)col;
      float u = jax_uniform01(kb0, kb1, idx);
      Hout[idx] = (u < p) ? (uint8_t)1 : (uint8_t)0;
    }
  }
}

// GEMM2: mu_v = H @ W^T + mu ; Vout = mu_v + normal(kn)*std
// H [M x K] uint8 (K = 512), W [N x K] row-major (N = V = 3072)
__global__ __launch_bounds__(256)
void gemm_v_sample(const uint8_t* __restrict__ Hin, const float* __restrict__ Wm,
                   const float* __restrict__ muv, const float* __restrict__ stdv,
                   float* __restrict__ Vout,
                   uint32_t kn0, uint32_t kn1, int M, int N, int K) {
  __shared__ float As[KT][TS];
  __shared__ float Bs[KT][TS];
  const int tid = threadIdx.x;
  const int tx = tid & 15, ty = tid >> 4;
  const int mBase = blockIdx.y * TS, nBase = blockIdx.x * TS;
  float acc[4][4] = {};
  const int la_m = tid >> 2;        // 0..63 (also used as n index for B tile)
  const int la_k = (tid & 3) * 4;   // 0,4,8,12

  for (int k0 = 0; k0 < K; k0 += KT) {
    uchar4 a4 = *reinterpret_cast<const uchar4*>(&Hin[(size_t)(mBase + la_m) * K + k0 + la_k]);
    As[la_k + 0][la_m] = (float)a4.x;
    As[la_k + 1][la_m] = (float)a4.y;
    As[la_k + 2][la_m] = (float)a4.z;
    As[la_k + 3][la_m] = (float)a4.w;
    float4 bv = *reinterpret_cast<const float4*>(&Wm[(size_t)(nBase + la_m) * K + k0 + la_k]);
    Bs[la_k + 0][la_m] = bv.x;
    Bs[la_k + 1][la_m] = bv.y;
    Bs[la_k + 2][la_m] = bv.z;
    Bs[la_k + 3][la_m] = bv.w;
    __syncthreads();
#pragma unroll
    for (int kk = 0; kk < KT; ++kk) {
      float4 a = *reinterpret_cast<const float4*>(&As[kk][ty * 4]);
      float4 b = *reinterpret_cast<const float4*>(&Bs[kk][tx * 4]);
      float ar[4] = {a.x, a.y, a.z, a.w};
      float br[4] = {b.x, b.y, b.z, b.w};
#pragma unroll
      for (int i = 0; i < 4; ++i)
#pragma unroll
        for (int j = 0; j < 4; ++j)
          acc[i][j] = fmaf(ar[i], br[j], acc[i][j]);
    }
    __syncthreads();
  }

  const float LO = -0.99999994f;         // nextafter(-1, 0) in f32
  const float SQRT2 = 1.41421356237f;    // rounds to 0x3FB504F3
#pragma unroll
  for (int i = 0; i < 4; ++i) {
    int row = mBase + ty * 4 + i;
#pragma unroll
    for (int j = 0; j < 4; ++j) {
      int col = nBase + tx * 4 + j;
      float m_v = acc[i][j] + muv[col];
      uint32_t idx = (uint32_t)row * (uint32_t)N + (uint32_t)col;
      float f = jax_uniform01(kn0, kn1, idx);
      float u = fmaxf(LO, fmaf(f, 2.0f, LO));   // f*2 is exact; matches mul+add
      float nz = SQRT2 * erfinv_xla(u);
      Vout[idx] = m_v + nz * stdv[col];
    }
  }
}

extern "C" void kernel_launch(void* const* d_in, const int* in_sizes, int n_in,
                              void* d_out, int out_size, void* d_ws, size_t ws_size,
                              hipStream_t stream) {
  const int B = 4096, V = 3072, H = 512, NUM_STEPS = 8;
  const float* v_in    = (const float*)d_in[0];
  const float* W       = (const float*)d_in[1];
  const float* b       = (const float*)d_in[2];
  const float* mu      = (const float*)d_in[3];
  const float* log_var = (const float*)d_in[4];
  float* out = (float*)d_out;

  float* invvar = (float*)d_ws;
  float* stdv   = invvar + V;
  uint8_t* h    = (uint8_t*)(stdv + V);   // B*H bytes = 2 MiB

  // ---- host-side key derivation (deterministic, partitionable threefry) ----
  // key(42) -> (0,42); split(key): child i = threefry(key, (0,i))
  uint32_t k0a, k0b, kl0, kl1;
  threefry2x32(0u, 42u, 0u, 0u, k0a, k0b);   // k0  (initial bernoulli)
  threefry2x32(0u, 42u, 0u, 1u, kl0, kl1);   // kloop
  uint32_t kn0[NUM_STEPS], kn1[NUM_STEPS], kb0[NUM_STEPS], kb1[NUM_STEPS];
  for (int t = 0; t < NUM_STEPS; ++t) {
    uint32_t kt0, kt1;
    threefry2x32(kl0, kl1, 0u, (uint32_t)t, kt0, kt1);  // keys[t]
    threefry2x32(kt0, kt1, 0u, 0u, kn0[t], kn1[t]);     // kn
    threefry2x32(kt0, kt1, 0u, 1u, kb0[t], kb1[t]);     // kb
  }

  prep_kernel<<<(V + 255) / 256, 256, 0, stream>>>(log_var, invvar, stdv, V);

  dim3 grid1(H / TS, B / TS);   // logits GEMM: N=512 -> 8, M=4096 -> 64
  dim3 grid2(V / TS, B / TS);   // v GEMM:      N=3072 -> 48, M -> 64

  // h0 = bernoulli(k0, sigmoid((v/var)@W + b))
  gemm_logit_bern<<<grid1, 256, 0, stream>>>(v_in, W, b, invvar, h, k0a, k0b, B, H, V);

  for (int t = 0; t < NUM_STEPS; ++t) {
    float* vt = out + (size_t)t * B * V;
    gemm_v_sample<<<grid2, 256, 0, stream>>>(h, W, mu, stdv, vt, kn0[t], kn1[t], B, V, H);
    if (t < NUM_STEPS - 1) {
      gemm_logit_bern<<<grid1, 256, 0, stream>>>(vt, W, b, invvar, h, kb0[t], kb1[t], B, H, V);
    }
  }
}